// Round 11
// baseline (127.059 us; speedup 1.0000x reference)
//
#include <hip/hip_runtime.h>

// SlotEquivariantHead: 16-step digit scan; per step MLP 162->256->256->96, 32 carry fed back.
// Round 11 = R4 (best: 93us rocprof / 80us timed, zero spill) + wave-parity SKEW ONLY:
// each wave starts its m-tile loop (P1/P2) and kk loop (P3) at a parity-dependent offset,
// decorrelating read-bursts vs MFMA-bursts of the 2 waves sharing a SIMD. Zero extra
// registers / instructions / layout changes — pure A/B against R4.
// 8 waves/block, 64 rows/block, grid 256, 2 waves/SIMD. W1/W2 frags in VGPRs, W3 in LDS.

typedef __attribute__((ext_vector_type(8))) short bf16x8;
typedef __attribute__((ext_vector_type(4))) float f32x4;
typedef __attribute__((ext_vector_type(2))) unsigned int u32x2;
typedef __attribute__((ext_vector_type(4))) unsigned int u32x4;

#define LDS_XAB 0        // 16 KB: [64 r][128 k] bf16, 256B rows, swz chunk^(r&15)
#define LDS_XC  16384    //  8 KB: [64 r][64 k]  bf16, 128B rows, swz chunk^(r&7)
#define LDS_H1  24576    // 32 KB: [64 r][256 n] bf16, 512B rows, swz chunk^(r&15)
#define LDS_H2  57344    // 32 KB
#define LDS_W3  90112    // 48 KB packed W3 fragments (frag-linear)
#define LDS_TOTAL 139264

__device__ inline unsigned short f32_to_bf16(float f) {
  unsigned int u = __builtin_bit_cast(unsigned int, f);
  u += 0x7FFFu + ((u >> 16) & 1u);
  return (unsigned short)(u >> 16);
}

__device__ inline unsigned int cvt_pk_bf16(float lo, float hi) {
  unsigned int r;
  asm("v_cvt_pk_bf16_f32 %0, %1, %2" : "=v"(r) : "v"(lo), "v"(hi));
  return r;
}

// Pack W1 (rows permuted, K-pad 192), W2 (256x256), W3 (256x96) into bf16 MFMA fragment
// layout: frag(kk,nt): lane l, elem j <- W[kk*32 + (l>>4)*8 + j][nt*16 + (l&15)].
// W1 row permutation k' -> source row: [0,128) a|b direct; [128,160) carry = 130+(k'-128);
// {160,161} op = 128+(k'-160); [162,192) zero.  (matches XC tail = [carry|op|pad])
__global__ void pack_weights_kernel(const float* __restrict__ W1,
                                    const float* __restrict__ W2,
                                    const float* __restrict__ W3,
                                    unsigned short* __restrict__ wp) {
  int idx = blockIdx.x * 256 + threadIdx.x;
  if (idx >= 139264) return;
  int j, lane, frag, nt, kk, k, n;
  float v = 0.0f;
  if (idx < 49152) {
    int e = idx;
    j = e & 7; lane = (e >> 3) & 63; frag = e >> 9;
    nt = frag % 16; kk = frag / 16;
    k = kk * 32 + ((lane >> 4) << 3) + j;
    n = nt * 16 + (lane & 15);
    int ksrc;
    if (k < 128)      ksrc = k;
    else if (k < 160) ksrc = 130 + (k - 128);   // carry rows
    else if (k < 162) ksrc = 128 + (k - 160);   // op rows
    else              ksrc = -1;                 // zero pad
    v = (ksrc >= 0) ? W1[ksrc * 256 + n] : 0.0f;
  } else if (idx < 114688) {
    int e = idx - 49152;
    j = e & 7; lane = (e >> 3) & 63; frag = e >> 9;
    nt = frag % 16; kk = frag / 16;
    k = kk * 32 + ((lane >> 4) << 3) + j;
    n = nt * 16 + (lane & 15);
    v = W2[k * 256 + n];
  } else {
    int e = idx - 114688;
    j = e & 7; lane = (e >> 3) & 63; frag = e >> 9;
    nt = frag % 6; kk = frag / 6;
    k = kk * 32 + ((lane >> 4) << 3) + j;
    n = nt * 16 + (lane & 15);
    v = W3[k * 96 + n];
  }
  wp[idx] = f32_to_bf16(v);
}

__global__ __launch_bounds__(512, 2) void scan_kernel(
    const float* __restrict__ Ain, const float* __restrict__ Bin,
    const float* __restrict__ Op,
    const float* __restrict__ b1, const float* __restrict__ b2,
    const float* __restrict__ b3,
    const unsigned short* __restrict__ wp,
    float* __restrict__ out) {
  extern __shared__ char lds[];

  const int tid  = threadIdx.x;
  const int wave = tid >> 6, lane = tid & 63;
  const int lcol = lane & 15;      // batch-row within tile
  const int q    = lane >> 4;      // k-quad for reads; n-quad for writes
  const int row0 = blockIdx.x * 64;
  const int mw = wave >> 1, ngg = wave & 1;
  const int skew2 = ((wave ^ (wave >> 2)) & 1) << 1;   // m-loop start offset (0 or 2)
  const int skew4 = skew2 << 1;                        // kk-loop start offset (0 or 4)

  // ---- persistent weight fragments: wave owns nt = wave*2 + n (n = 0,1)
  bf16x8 w1f[12], w2f[16];
  {
    const char* wb = (const char*)wp;
    #pragma unroll
    for (int kk = 0; kk < 6; ++kk)
      #pragma unroll
      for (int n = 0; n < 2; ++n)
        w1f[kk*2+n] = *(const bf16x8*)(wb + (size_t)(kk*16 + wave*2 + n)*1024 + lane*16);
    const char* wb2 = wb + 98304;
    #pragma unroll
    for (int kk = 0; kk < 8; ++kk)
      #pragma unroll
      for (int n = 0; n < 2; ++n)
        w2f[kk*2+n] = *(const bf16x8*)(wb2 + (size_t)(kk*16 + wave*2 + n)*1024 + lane*16);
  }
  // ---- bias vectors for accumulator init (4 consecutive channels per lane)
  f32x4 b1i[2], b2i[2], b3i[3];
  #pragma unroll
  for (int n = 0; n < 2; ++n)
    #pragma unroll
    for (int i = 0; i < 4; ++i) {
      b1i[n][i] = b1[(wave*2+n)*16 + q*4 + i];
      b2i[n][i] = b2[(wave*2+n)*16 + q*4 + i];
    }
  #pragma unroll
  for (int j = 0; j < 3; ++j)
    #pragma unroll
    for (int i = 0; i < 4; ++i)
      b3i[j][i] = b3[(ngg*3+j)*16 + q*4 + i];

  // ---- W3 fragments -> LDS (one-time, frag-linear => lane-linear conflict-free reads)
  {
    const char* w3src = (const char*)wp + 229376;
    #pragma unroll
    for (int i = 0; i < 6; ++i)
      *(u32x4*)(lds + LDS_W3 + (size_t)(tid + i*512)*16) =
          *(const u32x4*)(w3src + (size_t)(tid + i*512)*16);
  }
  // ---- XC init: k 0..31 carry=0, 32..33 op, 34..63 zero
  for (int i = tid; i < 4096; i += 512) {
    int r = i >> 6, kx = i & 63;
    unsigned short v = 0;
    if (kx == 32 || kx == 33) v = f32_to_bf16(Op[(size_t)(row0 + r)*2 + (kx - 32)]);
    int chunk = kx >> 3, within = (kx & 7) * 2;
    *(unsigned short*)(lds + LDS_XC + r*128 + ((chunk ^ (r & 7)) << 4) + within) = v;
  }

  // ---- a/b staging: thread covers row srow, 16 floats at part*16 of the 128-col [a|b] row
  const int part = tid & 7;
  const int srow = tid >> 3;
  const float* srcp = (part < 4 ? Ain : Bin) + (size_t)(row0 + srow)*1024 + (part & 3)*16;
  float4 pf[4];

  {  // p=0 synchronous stage + p=1 prefetch
    #pragma unroll
    for (int jj = 0; jj < 4; ++jj) pf[jj] = *(const float4*)(srcp + jj*4);
    unsigned int u[8];
    #pragma unroll
    for (int jj = 0; jj < 4; ++jj) {
      u[jj*2]   = cvt_pk_bf16(pf[jj].x, pf[jj].y);
      u[jj*2+1] = cvt_pk_bf16(pf[jj].z, pf[jj].w);
    }
    u32x4 t0 = {u[0],u[1],u[2],u[3]}, t1 = {u[4],u[5],u[6],u[7]};
    *(u32x4*)(lds + LDS_XAB + srow*256 + (((part*2)   ^ (srow & 15)) << 4)) = t0;
    *(u32x4*)(lds + LDS_XAB + srow*256 + (((part*2+1) ^ (srow & 15)) << 4)) = t1;
    #pragma unroll
    for (int jj = 0; jj < 4; ++jj) pf[jj] = *(const float4*)(srcp + 64 + jj*4);
  }
  __syncthreads();

  #pragma unroll 1
  for (int p = 0; p < 16; ++p) {
    // ============ phase 1: Y^T = W1^T @ X^T -> relu -> H1 [64r][256n] ============
    {
      f32x4 acc[2][4];   // [n][mi]  (mi -> tile (mi+skew2)&3)
      #pragma unroll
      for (int n = 0; n < 2; ++n)
        #pragma unroll
        for (int mi = 0; mi < 4; ++mi) { acc[0][mi] = b1i[0]; acc[1][mi] = b1i[1]; }
      #pragma unroll
      for (int mi = 0; mi < 4; ++mi) {
        const int m = (mi + skew2) & 3;
        const int r = m*16 + lcol;
        bf16x8 xf[6];
        #pragma unroll
        for (int kk = 0; kk < 4; ++kk)
          xf[kk] = *(const bf16x8*)(lds + LDS_XAB + r*256 + (((4*kk + q) ^ lcol) << 4));
        #pragma unroll
        for (int kk = 0; kk < 2; ++kk)
          xf[4+kk] = *(const bf16x8*)(lds + LDS_XC + r*128 + (((4*kk + q) ^ (lcol & 7)) << 4));
        __builtin_amdgcn_s_setprio(1);
        #pragma unroll
        for (int kk = 0; kk < 6; ++kk) {
          acc[0][mi] = __builtin_amdgcn_mfma_f32_16x16x32_bf16(w1f[kk*2+0], xf[kk], acc[0][mi], 0,0,0);
          acc[1][mi] = __builtin_amdgcn_mfma_f32_16x16x32_bf16(w1f[kk*2+1], xf[kk], acc[1][mi], 0,0,0);
        }
        __builtin_amdgcn_s_setprio(0);
      }
      #pragma unroll
      for (int n = 0; n < 2; ++n) {
        const int nbyte = (wave*2+n)*32 + q*8;
        const int chunk = nbyte >> 4, within = nbyte & 15;
        #pragma unroll
        for (int mi = 0; mi < 4; ++mi) {
          const int r = ((mi + skew2) & 3)*16 + lcol;
          float v0 = fmaxf(acc[n][mi][0], 0.f);
          float v1 = fmaxf(acc[n][mi][1], 0.f);
          float v2 = fmaxf(acc[n][mi][2], 0.f);
          float v3 = fmaxf(acc[n][mi][3], 0.f);
          u32x2 t; t.x = cvt_pk_bf16(v0, v1); t.y = cvt_pk_bf16(v2, v3);
          *(u32x2*)(lds + LDS_H1 + r*512 + ((chunk ^ lcol) << 4) + within) = t;
        }
      }
    }
    __syncthreads();  // B1

    // ---- stage XAB(p+1) from pf; prefetch p+2 ----
    if (p < 15) {
      unsigned int u[8];
      #pragma unroll
      for (int jj = 0; jj < 4; ++jj) {
        u[jj*2]   = cvt_pk_bf16(pf[jj].x, pf[jj].y);
        u[jj*2+1] = cvt_pk_bf16(pf[jj].z, pf[jj].w);
      }
      u32x4 t0 = {u[0],u[1],u[2],u[3]}, t1 = {u[4],u[5],u[6],u[7]};
      *(u32x4*)(lds + LDS_XAB + srow*256 + (((part*2)   ^ (srow & 15)) << 4)) = t0;
      *(u32x4*)(lds + LDS_XAB + srow*256 + (((part*2+1) ^ (srow & 15)) << 4)) = t1;
      if (p < 14) {
        const float* s2 = srcp + (p+2)*64;
        #pragma unroll
        for (int jj = 0; jj < 4; ++jj) pf[jj] = *(const float4*)(s2 + jj*4);
      }
    }

    // ============ phase 2: W2^T @ H1^T -> relu -> H2 ============
    {
      f32x4 acc[2][4];
      #pragma unroll
      for (int mi = 0; mi < 4; ++mi) { acc[0][mi] = b2i[0]; acc[1][mi] = b2i[1]; }
      #pragma unroll
      for (int mi = 0; mi < 4; ++mi) {
        const int m = (mi + skew2) & 3;
        const int r = m*16 + lcol;
        bf16x8 hf[8];
        #pragma unroll
        for (int kk = 0; kk < 8; ++kk)
          hf[kk] = *(const bf16x8*)(lds + LDS_H1 + r*512 + (((4*kk + q) ^ lcol) << 4));
        __builtin_amdgcn_s_setprio(1);
        #pragma unroll
        for (int kk = 0; kk < 8; ++kk) {
          acc[0][mi] = __builtin_amdgcn_mfma_f32_16x16x32_bf16(w2f[kk*2+0], hf[kk], acc[0][mi], 0,0,0);
          acc[1][mi] = __builtin_amdgcn_mfma_f32_16x16x32_bf16(w2f[kk*2+1], hf[kk], acc[1][mi], 0,0,0);
        }
        __builtin_amdgcn_s_setprio(0);
      }
      #pragma unroll
      for (int n = 0; n < 2; ++n) {
        const int nbyte = (wave*2+n)*32 + q*8;
        const int chunk = nbyte >> 4, within = nbyte & 15;
        #pragma unroll
        for (int mi = 0; mi < 4; ++mi) {
          const int r = ((mi + skew2) & 3)*16 + lcol;
          float v0 = fmaxf(acc[n][mi][0], 0.f);
          float v1 = fmaxf(acc[n][mi][1], 0.f);
          float v2 = fmaxf(acc[n][mi][2], 0.f);
          float v3 = fmaxf(acc[n][mi][3], 0.f);
          u32x2 t; t.x = cvt_pk_bf16(v0, v1); t.y = cvt_pk_bf16(v2, v3);
          *(u32x2*)(lds + LDS_H2 + r*512 + ((chunk ^ lcol) << 4) + within) = t;
        }
      }
    }
    __syncthreads();  // B2

    // ============ phase 3: W3^T @ H2^T -> y; nt<4 -> out (float4), nt 4,5 -> carry ============
    {
      f32x4 acc3[3] = {b3i[0], b3i[1], b3i[2]};
      const int r = mw*16 + lcol;
      #pragma unroll
      for (int kki = 0; kki < 8; ++kki) {
        const int kk = (kki + skew4) & 7;
        bf16x8 hf = *(const bf16x8*)(lds + LDS_H2 + r*512 + (((4*kk + q) ^ lcol) << 4));
        #pragma unroll
        for (int j = 0; j < 3; ++j) {
          bf16x8 wf = *(const bf16x8*)(lds + LDS_W3 + (size_t)(kk*6 + ngg*3 + j)*1024 + lane*16);
          acc3[j] = __builtin_amdgcn_mfma_f32_16x16x32_bf16(wf, hf, acc3[j], 0,0,0);
        }
      }
      #pragma unroll
      for (int j = 0; j < 3; ++j) {
        const int nt = ngg*3 + j;
        if (nt < 4) {
          float4 o;
          o.x = acc3[j][0]; o.y = acc3[j][1]; o.z = acc3[j][2]; o.w = acc3[j][3];
          *(float4*)&out[(size_t)(row0 + r)*1024 + p*64 + nt*16 + q*4] = o;
        } else {
          const int kbyte = (nt-4)*32 + q*8;            // carry channels at XC k 0..31
          const int chunk = kbyte >> 4, within = kbyte & 15;
          u32x2 t;
          t.x = cvt_pk_bf16(acc3[j][0], acc3[j][1]);
          t.y = cvt_pk_bf16(acc3[j][2], acc3[j][3]);
          *(u32x2*)(lds + LDS_XC + r*128 + ((chunk ^ (r & 7)) << 4) + within) = t;
        }
      }
    }
    __syncthreads();  // B3
  }
}

extern "C" void kernel_launch(void* const* d_in, const int* in_sizes, int n_in,
                              void* d_out, int out_size, void* d_ws, size_t ws_size,
                              hipStream_t stream) {
  const float* bias_a = (const float*)d_in[0];
  const float* bias_b = (const float*)d_in[1];
  const float* op     = (const float*)d_in[2];
  const float* W1     = (const float*)d_in[3];
  const float* b1     = (const float*)d_in[4];
  const float* W2     = (const float*)d_in[5];
  const float* b2     = (const float*)d_in[6];
  const float* W3     = (const float*)d_in[7];
  const float* b3     = (const float*)d_in[8];
  float* out = (float*)d_out;
  unsigned short* wp = (unsigned short*)d_ws;

  hipFuncSetAttribute((const void*)scan_kernel,
                      hipFuncAttributeMaxDynamicSharedMemorySize, LDS_TOTAL);

  pack_weights_kernel<<<544, 256, 0, stream>>>(W1, W2, W3, wp);
  scan_kernel<<<256, 512, LDS_TOTAL, stream>>>(bias_a, bias_b, op, b1, b2, b3, wp, out);
}

// Round 12
// 79.861 us; speedup vs baseline: 1.5910x; 1.5910x over previous
//
#include <hip/hip_runtime.h>

// SlotEquivariantHead: 16-step digit scan; per step MLP 162->256->256->96, 32 carry fed back.
// FINAL = Round-4 kernel restored byte-identical (best measured: 80.3us timed / 93us rocprof,
// zero spill, absmax 0.0156). Swapped-operand MFMA (Y^T = W^T @ X^T) so the C-fragment is
// 4 consecutive CHANNELS at fixed batch-row -> epilogue = one ds_write_b64 per tile into
// row-major H, float4 global stores. 8 waves/block (512 thr), 64 rows/block, grid 256,
// 2 waves/SIMD. W1/W2 frags in VGPRs (112 regs — at the allocator wall; R5-R11 showed any
// push past it spills), W3 frags in LDS. Bias folded into acc init.
// X layout: XAB [64r][128k] (a|b); XC [64r][64k] tail = [carry(32)|op(2)|zero-pad(30)]
// (W1 rows permuted at pack time to match).

typedef __attribute__((ext_vector_type(8))) short bf16x8;
typedef __attribute__((ext_vector_type(4))) float f32x4;
typedef __attribute__((ext_vector_type(2))) unsigned int u32x2;
typedef __attribute__((ext_vector_type(4))) unsigned int u32x4;

#define LDS_XAB 0        // 16 KB: [64 r][128 k] bf16, 256B rows, 16 chunks, swz chunk^(r&15)
#define LDS_XC  16384    //  8 KB: [64 r][64 k]  bf16, 128B rows,  8 chunks, swz chunk^(r&7)
#define LDS_H1  24576    // 32 KB: [64 r][256 n] bf16, 512B rows, 32 chunks, swz chunk^(r&15)
#define LDS_H2  57344    // 32 KB
#define LDS_W3  90112    // 48 KB packed W3 fragments (frag-linear)
#define LDS_TOTAL 139264

__device__ inline unsigned short f32_to_bf16(float f) {
  unsigned int u = __builtin_bit_cast(unsigned int, f);
  u += 0x7FFFu + ((u >> 16) & 1u);
  return (unsigned short)(u >> 16);
}

__device__ inline unsigned int cvt_pk_bf16(float lo, float hi) {
  unsigned int r;
  asm("v_cvt_pk_bf16_f32 %0, %1, %2" : "=v"(r) : "v"(lo), "v"(hi));
  return r;
}

// Pack W1 (rows permuted, K-pad 192), W2 (256x256), W3 (256x96) into bf16 MFMA fragment
// layout: frag(kk,nt): lane l, elem j <- W[kk*32 + (l>>4)*8 + j][nt*16 + (l&15)].
// W1 row permutation k' -> source row: [0,128) a|b direct; [128,160) carry = 130+(k'-128);
// {160,161} op = 128+(k'-160); [162,192) zero.  (matches XC tail = [carry|op|pad])
__global__ void pack_weights_kernel(const float* __restrict__ W1,
                                    const float* __restrict__ W2,
                                    const float* __restrict__ W3,
                                    unsigned short* __restrict__ wp) {
  int idx = blockIdx.x * 256 + threadIdx.x;
  if (idx >= 139264) return;
  int j, lane, frag, nt, kk, k, n;
  float v = 0.0f;
  if (idx < 49152) {
    int e = idx;
    j = e & 7; lane = (e >> 3) & 63; frag = e >> 9;
    nt = frag % 16; kk = frag / 16;
    k = kk * 32 + ((lane >> 4) << 3) + j;
    n = nt * 16 + (lane & 15);
    int ksrc;
    if (k < 128)      ksrc = k;
    else if (k < 160) ksrc = 130 + (k - 128);   // carry rows
    else if (k < 162) ksrc = 128 + (k - 160);   // op rows
    else              ksrc = -1;                 // zero pad
    v = (ksrc >= 0) ? W1[ksrc * 256 + n] : 0.0f;
  } else if (idx < 114688) {
    int e = idx - 49152;
    j = e & 7; lane = (e >> 3) & 63; frag = e >> 9;
    nt = frag % 16; kk = frag / 16;
    k = kk * 32 + ((lane >> 4) << 3) + j;
    n = nt * 16 + (lane & 15);
    v = W2[k * 256 + n];
  } else {
    int e = idx - 114688;
    j = e & 7; lane = (e >> 3) & 63; frag = e >> 9;
    nt = frag % 6; kk = frag / 6;
    k = kk * 32 + ((lane >> 4) << 3) + j;
    n = nt * 16 + (lane & 15);
    v = W3[k * 96 + n];
  }
  wp[idx] = f32_to_bf16(v);
}

__global__ __launch_bounds__(512, 2) void scan_kernel(
    const float* __restrict__ Ain, const float* __restrict__ Bin,
    const float* __restrict__ Op,
    const float* __restrict__ b1, const float* __restrict__ b2,
    const float* __restrict__ b3,
    const unsigned short* __restrict__ wp,
    float* __restrict__ out) {
  extern __shared__ char lds[];

  const int tid  = threadIdx.x;
  const int wave = tid >> 6, lane = tid & 63;
  const int lcol = lane & 15;      // batch-row within tile (D "col")
  const int q    = lane >> 4;      // k-quad for reads; n-quad for writes
  const int row0 = blockIdx.x * 64;
  const int mw = wave >> 1, ngg = wave & 1;

  // ---- persistent weight fragments: wave owns nt = wave*2 + n (n = 0,1)
  bf16x8 w1f[12], w2f[16];
  {
    const char* wb = (const char*)wp;
    #pragma unroll
    for (int kk = 0; kk < 6; ++kk)
      #pragma unroll
      for (int n = 0; n < 2; ++n)
        w1f[kk*2+n] = *(const bf16x8*)(wb + (size_t)(kk*16 + wave*2 + n)*1024 + lane*16);
    const char* wb2 = wb + 98304;
    #pragma unroll
    for (int kk = 0; kk < 8; ++kk)
      #pragma unroll
      for (int n = 0; n < 2; ++n)
        w2f[kk*2+n] = *(const bf16x8*)(wb2 + (size_t)(kk*16 + wave*2 + n)*1024 + lane*16);
  }
  // ---- bias vectors for accumulator init (4 consecutive channels per lane)
  f32x4 b1i[2], b2i[2], b3i[3];
  #pragma unroll
  for (int n = 0; n < 2; ++n)
    #pragma unroll
    for (int i = 0; i < 4; ++i) {
      b1i[n][i] = b1[(wave*2+n)*16 + q*4 + i];
      b2i[n][i] = b2[(wave*2+n)*16 + q*4 + i];
    }
  #pragma unroll
  for (int j = 0; j < 3; ++j)
    #pragma unroll
    for (int i = 0; i < 4; ++i)
      b3i[j][i] = b3[(ngg*3+j)*16 + q*4 + i];

  // ---- W3 fragments -> LDS (one-time, frag-linear => lane-linear conflict-free reads)
  {
    const char* w3src = (const char*)wp + 229376;
    #pragma unroll
    for (int i = 0; i < 6; ++i)
      *(u32x4*)(lds + LDS_W3 + (size_t)(tid + i*512)*16) =
          *(const u32x4*)(w3src + (size_t)(tid + i*512)*16);
  }
  // ---- XC init: k 0..31 carry=0, 32..33 op, 34..63 zero
  for (int i = tid; i < 4096; i += 512) {
    int r = i >> 6, kx = i & 63;
    unsigned short v = 0;
    if (kx == 32 || kx == 33) v = f32_to_bf16(Op[(size_t)(row0 + r)*2 + (kx - 32)]);
    int chunk = kx >> 3, within = (kx & 7) * 2;
    *(unsigned short*)(lds + LDS_XC + r*128 + ((chunk ^ (r & 7)) << 4) + within) = v;
  }

  // ---- a/b staging: thread covers row srow, 16 floats at part*16 of the 128-col [a|b] row
  const int part = tid & 7;
  const int srow = tid >> 3;
  const float* srcp = (part < 4 ? Ain : Bin) + (size_t)(row0 + srow)*1024 + (part & 3)*16;
  float4 pf[4];

  {  // p=0 synchronous stage + p=1 prefetch
    #pragma unroll
    for (int jj = 0; jj < 4; ++jj) pf[jj] = *(const float4*)(srcp + jj*4);
    unsigned int u[8];
    #pragma unroll
    for (int jj = 0; jj < 4; ++jj) {
      u[jj*2]   = cvt_pk_bf16(pf[jj].x, pf[jj].y);
      u[jj*2+1] = cvt_pk_bf16(pf[jj].z, pf[jj].w);
    }
    u32x4 t0 = {u[0],u[1],u[2],u[3]}, t1 = {u[4],u[5],u[6],u[7]};
    *(u32x4*)(lds + LDS_XAB + srow*256 + (((part*2)   ^ (srow & 15)) << 4)) = t0;
    *(u32x4*)(lds + LDS_XAB + srow*256 + (((part*2+1) ^ (srow & 15)) << 4)) = t1;
    #pragma unroll
    for (int jj = 0; jj < 4; ++jj) pf[jj] = *(const float4*)(srcp + 64 + jj*4);
  }
  __syncthreads();

  #pragma unroll 1
  for (int p = 0; p < 16; ++p) {
    // ============ phase 1: Y^T = W1^T @ X^T -> relu -> H1 [64r][256n] ============
    {
      f32x4 acc[2][4];   // [n][m-rtile]
      #pragma unroll
      for (int n = 0; n < 2; ++n)
        #pragma unroll
        for (int m = 0; m < 4; ++m) acc[n][m] = b1i[n];
      #pragma unroll
      for (int m = 0; m < 4; ++m) {
        const int r = m*16 + lcol;
        bf16x8 xf[6];
        #pragma unroll
        for (int kk = 0; kk < 4; ++kk)
          xf[kk] = *(const bf16x8*)(lds + LDS_XAB + r*256 + (((4*kk + q) ^ lcol) << 4));
        #pragma unroll
        for (int kk = 0; kk < 2; ++kk)
          xf[4+kk] = *(const bf16x8*)(lds + LDS_XC + r*128 + (((4*kk + q) ^ (lcol & 7)) << 4));
        __builtin_amdgcn_s_setprio(1);
        #pragma unroll
        for (int kk = 0; kk < 6; ++kk) {
          acc[0][m] = __builtin_amdgcn_mfma_f32_16x16x32_bf16(w1f[kk*2+0], xf[kk], acc[0][m], 0,0,0);
          acc[1][m] = __builtin_amdgcn_mfma_f32_16x16x32_bf16(w1f[kk*2+1], xf[kk], acc[1][m], 0,0,0);
        }
        __builtin_amdgcn_s_setprio(0);
      }
      #pragma unroll
      for (int n = 0; n < 2; ++n) {
        const int nbyte = (wave*2+n)*32 + q*8;          // (nt*16 + q*4) channels * 2B
        const int chunk = nbyte >> 4, within = nbyte & 15;
        #pragma unroll
        for (int m = 0; m < 4; ++m) {
          const int r = m*16 + lcol;
          float v0 = fmaxf(acc[n][m][0], 0.f);
          float v1 = fmaxf(acc[n][m][1], 0.f);
          float v2 = fmaxf(acc[n][m][2], 0.f);
          float v3 = fmaxf(acc[n][m][3], 0.f);
          u32x2 t; t.x = cvt_pk_bf16(v0, v1); t.y = cvt_pk_bf16(v2, v3);
          *(u32x2*)(lds + LDS_H1 + r*512 + ((chunk ^ lcol) << 4) + within) = t;
        }
      }
    }
    __syncthreads();  // B1

    // ---- stage XAB(p+1) from pf; prefetch p+2 ----
    if (p < 15) {
      unsigned int u[8];
      #pragma unroll
      for (int jj = 0; jj < 4; ++jj) {
        u[jj*2]   = cvt_pk_bf16(pf[jj].x, pf[jj].y);
        u[jj*2+1] = cvt_pk_bf16(pf[jj].z, pf[jj].w);
      }
      u32x4 t0 = {u[0],u[1],u[2],u[3]}, t1 = {u[4],u[5],u[6],u[7]};
      *(u32x4*)(lds + LDS_XAB + srow*256 + (((part*2)   ^ (srow & 15)) << 4)) = t0;
      *(u32x4*)(lds + LDS_XAB + srow*256 + (((part*2+1) ^ (srow & 15)) << 4)) = t1;
      if (p < 14) {
        const float* s2 = srcp + (p+2)*64;
        #pragma unroll
        for (int jj = 0; jj < 4; ++jj) pf[jj] = *(const float4*)(s2 + jj*4);
      }
    }

    // ============ phase 2: W2^T @ H1^T -> relu -> H2 ============
    {
      f32x4 acc[2][4];
      #pragma unroll
      for (int n = 0; n < 2; ++n)
        #pragma unroll
        for (int m = 0; m < 4; ++m) acc[n][m] = b2i[n];
      #pragma unroll
      for (int m = 0; m < 4; ++m) {
        const int r = m*16 + lcol;
        bf16x8 hf[8];
        #pragma unroll
        for (int kk = 0; kk < 8; ++kk)
          hf[kk] = *(const bf16x8*)(lds + LDS_H1 + r*512 + (((4*kk + q) ^ lcol) << 4));
        __builtin_amdgcn_s_setprio(1);
        #pragma unroll
        for (int kk = 0; kk < 8; ++kk) {
          acc[0][m] = __builtin_amdgcn_mfma_f32_16x16x32_bf16(w2f[kk*2+0], hf[kk], acc[0][m], 0,0,0);
          acc[1][m] = __builtin_amdgcn_mfma_f32_16x16x32_bf16(w2f[kk*2+1], hf[kk], acc[1][m], 0,0,0);
        }
        __builtin_amdgcn_s_setprio(0);
      }
      #pragma unroll
      for (int n = 0; n < 2; ++n) {
        const int nbyte = (wave*2+n)*32 + q*8;
        const int chunk = nbyte >> 4, within = nbyte & 15;
        #pragma unroll
        for (int m = 0; m < 4; ++m) {
          const int r = m*16 + lcol;
          float v0 = fmaxf(acc[n][m][0], 0.f);
          float v1 = fmaxf(acc[n][m][1], 0.f);
          float v2 = fmaxf(acc[n][m][2], 0.f);
          float v3 = fmaxf(acc[n][m][3], 0.f);
          u32x2 t; t.x = cvt_pk_bf16(v0, v1); t.y = cvt_pk_bf16(v2, v3);
          *(u32x2*)(lds + LDS_H2 + r*512 + ((chunk ^ lcol) << 4) + within) = t;
        }
      }
    }
    __syncthreads();  // B2

    // ============ phase 3: W3^T @ H2^T -> y; nt<4 -> out (float4), nt 4,5 -> carry ============
    {
      f32x4 acc3[3] = {b3i[0], b3i[1], b3i[2]};
      const int r = mw*16 + lcol;
      #pragma unroll
      for (int kk = 0; kk < 8; ++kk) {
        bf16x8 hf = *(const bf16x8*)(lds + LDS_H2 + r*512 + (((4*kk + q) ^ lcol) << 4));
        #pragma unroll
        for (int j = 0; j < 3; ++j) {
          bf16x8 wf = *(const bf16x8*)(lds + LDS_W3 + (size_t)(kk*6 + ngg*3 + j)*1024 + lane*16);
          acc3[j] = __builtin_amdgcn_mfma_f32_16x16x32_bf16(wf, hf, acc3[j], 0,0,0);
        }
      }
      #pragma unroll
      for (int j = 0; j < 3; ++j) {
        const int nt = ngg*3 + j;
        if (nt < 4) {
          float4 o;
          o.x = acc3[j][0]; o.y = acc3[j][1]; o.z = acc3[j][2]; o.w = acc3[j][3];
          *(float4*)&out[(size_t)(row0 + r)*1024 + p*64 + nt*16 + q*4] = o;
        } else {
          const int kbyte = (nt-4)*32 + q*8;            // carry channels at XC k 0..31
          const int chunk = kbyte >> 4, within = kbyte & 15;
          u32x2 t;
          t.x = cvt_pk_bf16(acc3[j][0], acc3[j][1]);
          t.y = cvt_pk_bf16(acc3[j][2], acc3[j][3]);
          *(u32x2*)(lds + LDS_XC + r*128 + ((chunk ^ (r & 7)) << 4) + within) = t;
        }
      }
    }
    __syncthreads();  // B3
  }
}

extern "C" void kernel_launch(void* const* d_in, const int* in_sizes, int n_in,
                              void* d_out, int out_size, void* d_ws, size_t ws_size,
                              hipStream_t stream) {
  const float* bias_a = (const float*)d_in[0];
  const float* bias_b = (const float*)d_in[1];
  const float* op     = (const float*)d_in[2];
  const float* W1     = (const float*)d_in[3];
  const float* b1     = (const float*)d_in[4];
  const float* W2     = (const float*)d_in[5];
  const float* b2     = (const float*)d_in[6];
  const float* W3     = (const float*)d_in[7];
  const float* b3     = (const float*)d_in[8];
  float* out = (float*)d_out;
  unsigned short* wp = (unsigned short*)d_ws;

  hipFuncSetAttribute((const void*)scan_kernel,
                      hipFuncAttributeMaxDynamicSharedMemorySize, LDS_TOTAL);

  pack_weights_kernel<<<544, 256, 0, stream>>>(W1, W2, W3, wp);
  scan_kernel<<<256, 512, LDS_TOTAL, stream>>>(bias_a, bias_b, op, b1, b2, b3, wp, out);
}